// Round 11
// baseline (631.392 us; speedup 1.0000x reference)
//
#include <hip/hip_runtime.h>
#include <hip/hip_bf16.h>

// LoRALinear: out = x @ (W + 2.0*B@A)^T + bias ; M=16384, N=4096, K=4096, R=16.
// Round 11: FRAGMENT-LINEAR layout for both operands (prep kernels write
// 32x16 MFMA fragments as contiguous 1KB blocks, lane l at frag*1024+l*16,
// mapping row=l&31, k=(l>>5)*8+e — verified by r3's passing 32x32 run).
// -> every LDS read is a contiguous 1KB wave read (conflict-free by
// construction, any shape) -> unblocks 32x32x16 MFMA (wall 2483->2066
// cyc/K-tile) with r10's proven schedule/ledger verbatim.
// ws layout: [0,134217728) x_frag_bf16 ; [134217728, +33554432) W_frag_bf16.

typedef __attribute__((ext_vector_type(8))) short bf16x8;
typedef __attribute__((ext_vector_type(16))) float f32x16;
typedef __attribute__((ext_vector_type(4))) unsigned short u16x4;

#define M_DIM 16384
#define N_DIM 4096
#define K_DIM 4096
#define NT 64   // K-tiles of BK=64 (4 k16-fragments each)

__device__ __forceinline__ unsigned short f2bf(float f) {
    unsigned int u = __builtin_bit_cast(unsigned int, f);
    unsigned int r = u + 0x7FFFu + ((u >> 16) & 1u);
    return (unsigned short)(r >> 16);
}

__device__ __forceinline__ void async16(const void* g, void* l) {
    __builtin_amdgcn_global_load_lds(
        (const __attribute__((address_space(1))) unsigned int*)g,
        (__attribute__((address_space(3))) unsigned int*)l,
        16, 0, 0);
}

// ---- prep 1: x fp32 -> fragment-linear bf16 -------------------------------
// frag = (m>>5)*256 + (k>>4); within frag, lane l holds (row=l&31,
// k'=(l>>5)*8+e) at elt frag*512 + l*8 + e. Wave writes 1KB contiguous.
__global__ void __launch_bounds__(256) cast_x_kernel(
    const float* __restrict__ x, unsigned short* __restrict__ y) {
    const int total = 512 * 256 * 64;   // frags x lanes = 8388608 tasks
    int idx = blockIdx.x * 256 + threadIdx.x;
    const int stride = gridDim.x * 256;
    for (; idx < total; idx += stride) {
        const int frag = idx >> 6, l = idx & 63;
        const int m = ((frag >> 8) << 5) + (l & 31);
        const int k = ((frag & 255) << 4) + ((l >> 5) << 3);
        const float4* px = reinterpret_cast<const float4*>(&x[(size_t)m * K_DIM + k]);
        float4 a = px[0], b = px[1];
        unsigned short r[8] = { f2bf(a.x), f2bf(a.y), f2bf(a.z), f2bf(a.w),
                                f2bf(b.x), f2bf(b.y), f2bf(b.z), f2bf(b.w) };
        *reinterpret_cast<bf16x8*>(&y[((size_t)frag << 9) + (l << 3)]) =
            *reinterpret_cast<const bf16x8*>(r);
    }
}

// ---- prep 2: W_eff = W + 2*B@A -> fragment-linear bf16 --------------------
__global__ void __launch_bounds__(256) weff_kernel(
    const float* __restrict__ W, const float* __restrict__ lA,
    const float* __restrict__ lB, unsigned short* __restrict__ out) {
    constexpr int K = K_DIM, R = 16;
    constexpr float S = 2.0f;  // 32.0 / 16
    int o = blockIdx.x;
    int t = threadIdx.x;
    float b[R];
#pragma unroll
    for (int r = 0; r < R; ++r) b[r] = lB[o * R + r];
#pragma unroll
    for (int c = 0; c < 4; ++c) {
        int i = c * 1024 + t * 4;
        float4 wv = *reinterpret_cast<const float4*>(&W[o * K + i]);
        float sx = 0.f, sy = 0.f, sz = 0.f, sw = 0.f;
#pragma unroll
        for (int r = 0; r < R; ++r) {
            float4 a = *reinterpret_cast<const float4*>(&lA[r * K + i]);
            sx += b[r] * a.x; sy += b[r] * a.y;
            sz += b[r] * a.z; sw += b[r] * a.w;
        }
        u16x4 ov = { f2bf(wv.x + S * sx), f2bf(wv.y + S * sy),
                     f2bf(wv.z + S * sz), f2bf(wv.w + S * sw) };
        const int frag = (o >> 5) * 256 + (i >> 4);
        const int lane_ = (o & 31) + (((i >> 3) & 1) << 5);
        *reinterpret_cast<u16x4*>(
            &out[((size_t)frag << 9) + (lane_ << 3) + (i & 7)]) = ov;
    }
}

// ---- main GEMM: 256x256 tile, 8-wave, 32x32x16 MFMA, frag-linear LDS ------
// LDS per buf: A 32 frags [0,32768) + B 32 frags [32768,65536); x2 dbuf.
// Stage: wave wid moves frags g=wid*4+j (j 0..3) per operand per tile.
#define ASTAGE(t, bsel, jlo, jhi)                                             \
    _Pragma("unroll") for (int j = (jlo); j <= (jhi); ++j) {                  \
        const int g = wid * 4 + j;                                            \
        async16(A + (((size_t)(bm * 8 + (g >> 2)) * 256 + (t) * 4 + (g & 3))  \
                     << 9) + (lane << 3),                                     \
                lds + (bsel) * 65536 + g * 1024 + (lane << 4));               \
    }

#define BSTAGE(t, bsel)                                                       \
    _Pragma("unroll") for (int j = 0; j < 4; ++j) {                           \
        const int g = wid * 4 + j;                                            \
        async16(B + (((size_t)(bn * 8 + (g >> 2)) * 256 + (t) * 4 + (g & 3))  \
                     << 9) + (lane << 3),                                     \
                lds + (bsel) * 65536 + 32768 + g * 1024 + (lane << 4));       \
    }

// contiguous-1KB fragment reads (conflict-free by construction)
#define LDA32(dst, mh, kh, bsel)                                              \
    _Pragma("unroll") for (int mm = 0; mm < 2; ++mm)                          \
    _Pragma("unroll") for (int kk = 0; kk < 2; ++kk)                          \
        dst[mm * 2 + kk] = *(const bf16x8*)(lds + (bsel) * 65536 +            \
            (((wm * 4 + (mh) * 2 + mm) * 4 + (kh) * 2 + kk) << 10) +          \
            (lane << 4));

#define LDB32(dst, kh, bsel)                                                  \
    _Pragma("unroll") for (int nn = 0; nn < 2; ++nn)                          \
    _Pragma("unroll") for (int kk = 0; kk < 2; ++kk)                          \
        dst[nn * 2 + kk] = *(const bf16x8*)(lds + (bsel) * 65536 + 32768 +    \
            (((wn * 2 + nn) * 4 + (kh) * 2 + kk) << 10) + (lane << 4));

// one cluster: 8 MFMA (mm2 x nn2 x kk2), acc indexed (mh*2+mm, nn)
#define MMQ(asrc, bsrc, mh)                                                   \
    __builtin_amdgcn_s_setprio(1);                                            \
    _Pragma("unroll") for (int kk = 0; kk < 2; ++kk)                          \
    _Pragma("unroll") for (int mm = 0; mm < 2; ++mm)                          \
    _Pragma("unroll") for (int nn = 0; nn < 2; ++nn)                          \
        acc[(mh) * 2 + mm][nn] = __builtin_amdgcn_mfma_f32_32x32x16_bf16(     \
            asrc[mm * 2 + kk], bsrc[nn * 2 + kk], acc[(mh) * 2 + mm][nn],     \
            0, 0, 0);                                                         \
    __builtin_amdgcn_s_setprio(0)

#define CFENCE() asm volatile("" ::: "memory")
#define WAIT_LGKM(n)                                                          \
    asm volatile("s_waitcnt lgkmcnt(" #n ")" ::: "memory");                   \
    __builtin_amdgcn_sched_barrier(0)

// r10's proven ledger, 32x32 clusters. lgkm walk: G0(8) G1(4) wait(4);
// G2(8) wait(8); G3(4) wait(4); barrier; wait(0).
// vmcnt at boundary: outstanding B(t+1)x4 + A(t+1)x4 + B(t+2)x4 = 12;
// vmcnt(4) keeps B(t+2), retires A(t+1)+B(t+1) (both read next tile).
#define KTILE(t)                                                              \
    {                                                                         \
        const int bs_ = (t) & 1, bo_ = bs_ ^ 1;                               \
        LDA32(arE, 0, 0, bs_);                  /* G0a: 4 */                  \
        LDB32(br0, 0, bs_);                     /* G0b: 4 */                  \
        if ((t) + 1 < NT) ASTAGE((t) + 1, bo_, 0, 1);                         \
        LDA32(arO, 1, 0, bs_);                  /* G1: 4 */                   \
        WAIT_LGKM(4);                                                         \
        MMQ(arE, br0, 0);                                                     \
        if ((t) + 1 < NT) ASTAGE((t) + 1, bo_, 2, 3);                         \
        LDA32(arE2, 0, 1, bs_);                 /* G2a: 4 */                  \
        LDB32(br1, 1, bs_);                     /* G2b: 4 */                  \
        WAIT_LGKM(8);                                                         \
        MMQ(arO, br0, 1);                                                     \
        LDA32(arO2, 1, 1, bs_);                 /* G3: 4 */                   \
        WAIT_LGKM(4);                                                         \
        MMQ(arE2, br1, 0);                                                    \
        CFENCE();                                                             \
        __builtin_amdgcn_s_barrier();   /* all B reads retired (G2 done) */   \
        CFENCE();                                                             \
        if ((t) + 2 < NT) BSTAGE((t) + 2, bs_);                               \
        WAIT_LGKM(0);                                                         \
        MMQ(arO2, br1, 1);                                                    \
        if ((t) < NT - 2) {                                                   \
            asm volatile("s_waitcnt vmcnt(4)" ::: "memory");                  \
        } else {                                                              \
            asm volatile("s_waitcnt vmcnt(0)" ::: "memory");                  \
        }                                                                     \
        __builtin_amdgcn_s_barrier();                                         \
        CFENCE();                                                             \
    }

__global__ void __launch_bounds__(512, 2) gemmfl_kernel(
    const unsigned short* __restrict__ A,
    const unsigned short* __restrict__ B,
    const float* __restrict__ bias,
    float* __restrict__ C) {
    __shared__ __align__(1024) char lds[131072];

    const int tid = threadIdx.x;
    const int lane = tid & 63, wid = tid >> 6;
    const int wm = wid >> 2, wn = wid & 3;   // 2 x 4 waves (128 x 64 outputs)
    const int lc = lane & 31, hi = lane >> 5;

    // XCD-aware swizzle: 1024 blocks (divisible by 8)
    const int bid = blockIdx.x;
    const int swz = (bid & 7) * 128 + (bid >> 3);
    const int bm = swz >> 4, bn = swz & 15;  // 64 x 16 tiles

    f32x16 acc[4][2] = {};
    bf16x8 arE[4], arO[4], arE2[4], arO2[4], br0[4], br1[4];

    // prologue: B(0)->buf0, A(0)->buf0, B(1)->buf1; vmcnt(4) keeps B(1)
    BSTAGE(0, 0);
    ASTAGE(0, 0, 0, 3);
    BSTAGE(1, 1);
    asm volatile("s_waitcnt vmcnt(4)" ::: "memory");
    __builtin_amdgcn_s_barrier();
    CFENCE();

#pragma unroll 2
    for (int t = 0; t < NT; ++t) {
        KTILE(t);
    }

    // epilogue: 32x32 D layout (r3-verified): col=lane&31,
    // row=(reg&3)+8*(reg>>2)+4*hi
    const int row0 = bm * 256 + wm * 128;
    const int col0 = bn * 256 + wn * 64;
#pragma unroll
    for (int n = 0; n < 2; ++n) {
        const int col = col0 + n * 32 + lc;
        const float bv = bias[col];
#pragma unroll
        for (int m = 0; m < 4; ++m) {
#pragma unroll
            for (int g = 0; g < 4; ++g) {
#pragma unroll
                for (int r = 0; r < 4; ++r) {
                    const int row = row0 + m * 32 + g * 8 + 4 * hi + r;
                    C[(size_t)row * N_DIM + col] = acc[m][n][g * 4 + r] + bv;
                }
            }
        }
    }
}

extern "C" void kernel_launch(void* const* d_in, const int* in_sizes, int n_in,
                              void* d_out, int out_size, void* d_ws, size_t ws_size,
                              hipStream_t stream) {
    const float* x    = (const float*)d_in[0];  // [4,4096,4096]
    const float* W    = (const float*)d_in[1];  // [4096,4096]
    const float* bias = (const float*)d_in[2];  // [4096]
    const float* lA   = (const float*)d_in[3];  // [16,4096]
    const float* lB   = (const float*)d_in[4];  // [4096,16]
    float* out = (float*)d_out;

    unsigned short* xb   = (unsigned short*)d_ws;                       // 134 MB
    unsigned short* weff = (unsigned short*)((char*)d_ws + 134217728);  // 32 MB

    cast_x_kernel<<<4096, 256, 0, stream>>>(x, xb);
    weff_kernel<<<N_DIM, 256, 0, stream>>>(W, lA, lB, weff);
    gemmfl_kernel<<<(M_DIM / 256) * (N_DIM / 256), 512, 0, stream>>>(
        xb, weff, bias, out);
}